// Round 8
// baseline (333.713 us; speedup 1.0000x reference)
//
#include <hip/hip_runtime.h>

// GRU H=31, B=2048, T=512, FC->2, three-phase:
//  1) pack_wih: W_ih -> packed f16 pairs in ws, PRE-SCALED (r/z rows x log2e,
//     n rows x 2log2e) so the recurrence uses v_exp (=2^x) natively.
//  2) xg_gemm:  xg[b][row][t] = (b_ih[row] + x . W_ih[row]) * scale  (f16, ws)
//  3) gru_rec2: ONE BATCH PER 2-WAVE BLOCK (2048 blocks = 4096 waves =
//     4 waves/SIMD). Row-parallel: each dot-lane owns ONE gate row
//     (16 dot2/step, h via LDS broadcast ds_read_b128 — no readlanes).
//       w0: lanes 0-30 r-rows, 32-62 n-rows, 63 FC0
//       w1: lanes 0-30 z-rows, 32-62 GATE lanes (unit=li-32), 63 FC1
//     Preacts: one unconditional ds_write_b64 {pre, xa} per lane into
//     pre2[128] (real slots r:u, z:31+u, n:62+u; distinct dummies for rest).
//     Gate lanes read {pr,pz,(pn,xn)}, 4-trans exp2 gate block, write h
//     (f16) to hbuf. Two __syncthreads()/step (preacts visible; h visible).

constexpr int BB = 2048, TT = 512, HH = 31;
constexpr int RR = 96;                                  // padded xg rows
constexpr size_t XG_BYTES = (size_t)BB * RR * TT * 2;   // 201326592
constexpr int WPAIRS = 93 * 16;
constexpr size_t WS_NEEDED = XG_BYTES + (size_t)WPAIRS * 4;
constexpr float LOG2E = 1.4426950408889634f;

#define MEMFENCE asm volatile("" ::: "memory")

typedef _Float16 hf2 __attribute__((ext_vector_type(2)));

__device__ __forceinline__ float dot2(int a, hf2 w, float acc) {
#if __has_builtin(__builtin_amdgcn_fdot2)
    return __builtin_amdgcn_fdot2(__builtin_bit_cast(hf2, a), w, acc, false);
#else
    hf2 x = __builtin_bit_cast(hf2, a);
    return acc + (float)x.x * (float)w.x + (float)x.y * (float)w.y;
#endif
}

__device__ __forceinline__ float fast_exp2(float x) {
#if __has_builtin(__builtin_amdgcn_exp2f)
    return __builtin_amdgcn_exp2f(x);
#else
    return exp2f(x);
#endif
}
__device__ __forceinline__ float fast_rcp(float x) {
#if __has_builtin(__builtin_amdgcn_rcpf)
    return __builtin_amdgcn_rcpf(x);
#else
    return __fdividef(1.f, x);
#endif
}

// ---------------- phase 1a: pack W_ih to scaled f16 pairs ----------------
__global__ void pack_wih_kernel(const float* __restrict__ W_ih, int* __restrict__ wpk) {
    int q = blockIdx.x * blockDim.x + threadIdx.x;
    if (q >= WPAIRS) return;
    int row = q >> 4, p = q & 15;
    const float s = (row < 62) ? LOG2E : 2.f * LOG2E;
    float lo = W_ih[row * HH + 2 * p] * s;
    float hi = (2 * p + 1 < HH) ? W_ih[row * HH + 2 * p + 1] * s : 0.f;
    hf2 w; w.x = (_Float16)lo; w.y = (_Float16)hi;
    wpk[q] = __builtin_bit_cast(int, w);
}

// ---------------- phase 1b: xg = (x @ W_ih^T + b_ih) * scale ----------------
__global__ __launch_bounds__(128, 2) void xg_gemm_kernel(
    const float* __restrict__ x, const int* __restrict__ wpk,
    const float* __restrict__ b_ih, _Float16* __restrict__ xg)
{
    const int tid = threadIdx.x;
    const int b   = blockIdx.x;
    const int t0  = tid * 4;                     // 4 consecutive timesteps
    const float* xb = x + ((size_t)b * TT + t0) * HH;

    hf2 xp[4][16];
#pragma unroll
    for (int j = 0; j < 4; ++j)
#pragma unroll
        for (int p = 0; p < 16; ++p) {
            float lo = xb[j * HH + 2 * p];
            float hi = (2 * p + 1 < HH) ? xb[j * HH + 2 * p + 1] : 0.f;
            xp[j][p].x = (_Float16)lo; xp[j][p].y = (_Float16)hi;
        }

    _Float16* xgb = xg + (size_t)b * RR * TT + t0;
    for (int row = 0; row < 93; ++row) {
        const float bi = b_ih[row] * ((row < 62) ? LOG2E : 2.f * LOG2E);
        float a0 = bi, a1 = bi, a2 = bi, a3 = bi;
        const int* wr = wpk + row * 16;                   // uniform -> s_load
#pragma unroll
        for (int p = 0; p < 16; ++p) {
            const int w = wr[p];
            a0 = dot2(w, xp[0][p], a0);
            a1 = dot2(w, xp[1][p], a1);
            a2 = dot2(w, xp[2][p], a2);
            a3 = dot2(w, xp[3][p], a3);
        }
        hf2 lo2; lo2.x = (_Float16)a0; lo2.y = (_Float16)a1;
        hf2 hi2; hi2.x = (_Float16)a2; hi2.y = (_Float16)a3;
        *reinterpret_cast<int2*>(xgb + (size_t)row * TT) =
            make_int2(__builtin_bit_cast(int, lo2), __builtin_bit_cast(int, hi2));
    }
    for (int row = 93; row < 96; ++row)       // zero pad rows
        *reinterpret_cast<int2*>(xgb + (size_t)row * TT) = make_int2(0, 0);
}

// ------- phase 2: recurrence, 1 batch per 2-wave block, row-parallel -------
__global__ __launch_bounds__(128, 4) void gru_rec2_kernel(
    const _Float16* __restrict__ xg, const float* __restrict__ W_hh,
    const float* __restrict__ b_hh, const float* __restrict__ W_fc,
    const float* __restrict__ b_fc, float* __restrict__ out)
{
    __shared__ float2    pre2[128];   // {preact, xa}; real slots 0..92
    __shared__ _Float16  hbuf[32];    // h as f16, unit i at [i], [31]=0 pad

    const int tid  = threadIdx.x;
    const int wave = tid >> 6;
    const int li   = tid & 63;
    const int b    = blockIdx.x;
    const int u    = li & 31;

    const bool loRole = (li < 31);                 // w0: R, w1: Z
    const bool hiRole = (li >= 32 && li < 63);     // w0: N, w1: GATE
    const bool isFC   = (li == 63);
    const bool isN    = (wave == 0) && hiRole;
    const bool isGate = (wave == 1) && hiRole;

    // Per-lane role constants.
    int   row   = 95;                 // xg pad row (zeros) for non-row lanes
    const float* wrow = nullptr;
    float scale = 0.f, bias = 0.f;
    int   slot  = 96 + (tid & 31);    // dummy write slot (96..127)
    if (loRole) {
        row = wave * 31 + u;          // r-row (w0) or z-row (w1)
        wrow = W_hh + (size_t)row * HH; scale = LOG2E;
        bias = LOG2E * b_hh[row];     slot = row;
    } else if (isN) {
        row = 62 + u;
        wrow = W_hh + (size_t)row * HH; scale = 2.f * LOG2E;
        bias = 2.f * LOG2E * b_hh[row]; slot = row;
    } else if (isFC) {
        wrow = W_fc + (size_t)wave * HH; scale = 1.f;
        bias = b_fc[wave];            // row stays 95 (xa = 0)
    }

    hf2 wD[16];
#pragma unroll
    for (int p = 0; p < 16; ++p) {
        float lo = wrow ? wrow[2 * p] * scale : 0.f;
        float hi = (wrow && 2 * p + 1 < HH) ? wrow[2 * p + 1] * scale : 0.f;
        wD[p].x = (_Float16)lo; wD[p].y = (_Float16)hi;
    }

    const _Float16* gA = xg + ((size_t)b * RR + row) * TT;
    float* outb = out + (size_t)b * TT * 2;

    if (tid < 32) hbuf[tid] = (_Float16)0.f;       // h_0 = 0 (incl pad)
    __syncthreads();

    const int4* HP = (const int4*)&hbuf[0];
    int4 hq0 = HP[0], hq1 = HP[1], hq2 = HP[2], hq3 = HP[3];

    float hold = 0.f;                               // gate lanes' h[u]
    int4 bufA = *(const int4*)gA;

    for (int tb = 0; tb < TT / 8; ++tb) {
        int4 nxtA = bufA;
        if (tb + 1 < TT / 8) nxtA = *(const int4*)(gA + (size_t)(tb + 1) * 8);
#pragma unroll
        for (int s = 0; s < 8; ++s) {
            const int t = tb * 8 + s;
            const float xa = (float)(((const _Float16*)&bufA)[s]);

            // ---- section A: row/FC dots on h_t ----
            float a0 = bias + (isN ? 0.f : xa), a1 = 0.f;
            a0 = dot2(hq0.x, wD[0],  a0); a1 = dot2(hq0.y, wD[1],  a1);
            a0 = dot2(hq0.z, wD[2],  a0); a1 = dot2(hq0.w, wD[3],  a1);
            a0 = dot2(hq1.x, wD[4],  a0); a1 = dot2(hq1.y, wD[5],  a1);
            a0 = dot2(hq1.z, wD[6],  a0); a1 = dot2(hq1.w, wD[7],  a1);
            a0 = dot2(hq2.x, wD[8],  a0); a1 = dot2(hq2.y, wD[9],  a1);
            a0 = dot2(hq2.z, wD[10], a0); a1 = dot2(hq2.w, wD[11], a1);
            a0 = dot2(hq3.x, wD[12], a0); a1 = dot2(hq3.y, wD[13], a1);
            a0 = dot2(hq3.z, wD[14], a0); a1 = dot2(hq3.w, wD[15], a1);
            const float acc = a0 + a1;

            pre2[slot] = make_float2(acc, xa);      // unconditional b64
            if (isFC && t > 0) outb[(size_t)(t - 1) * 2 + wave] = acc;

            __syncthreads();                        // preacts visible

            // ---- section B: gate lanes compute h_{t+1} ----
            if (isGate) {
                const float  pr = pre2[u].x;
                const float  pz = pre2[31 + u].x;
                const float2 pn = pre2[62 + u];
                const float r  = fast_rcp(1.f + fast_exp2(-pr));
                const float z  = fast_rcp(1.f + fast_exp2(-pz));
                const float en = fast_exp2(-fmaf(r, pn.x, pn.y));
                const float nn = fmaf(2.f, fast_rcp(1.f + en), -1.f);
                const float h  = nn + z * (hold - nn);
                hold = h;
                hbuf[u] = (_Float16)h;
            }
            __syncthreads();                        // h_{t+1} visible

            hq0 = HP[0]; hq1 = HP[1]; hq2 = HP[2]; hq3 = HP[3];
        }
        bufA = nxtA;
    }

    // epilogue: FC(h_T) -> out[TT-1]
    {
        float a0 = bias, a1 = 0.f;
        a0 = dot2(hq0.x, wD[0],  a0); a1 = dot2(hq0.y, wD[1],  a1);
        a0 = dot2(hq0.z, wD[2],  a0); a1 = dot2(hq0.w, wD[3],  a1);
        a0 = dot2(hq1.x, wD[4],  a0); a1 = dot2(hq1.y, wD[5],  a1);
        a0 = dot2(hq1.z, wD[6],  a0); a1 = dot2(hq1.w, wD[7],  a1);
        a0 = dot2(hq2.x, wD[8],  a0); a1 = dot2(hq2.y, wD[9],  a1);
        a0 = dot2(hq2.z, wD[10], a0); a1 = dot2(hq2.w, wD[11], a1);
        a0 = dot2(hq3.x, wD[12], a0); a1 = dot2(hq3.y, wD[13], a1);
        a0 = dot2(hq3.z, wD[14], a0); a1 = dot2(hq3.w, wD[15], a1);
        if (isFC) outb[(size_t)(TT - 1) * 2 + wave] = a0 + a1;
    }
}

// ---------------- fallback (round-3 kernel, used if ws too small) ----------------
__global__ __launch_bounds__(64, 1) void gru_pair_kernel(
    const float* __restrict__ x, const float* __restrict__ W_ih,
    const float* __restrict__ W_hh, const float* __restrict__ b_ih,
    const float* __restrict__ b_hh, const float* __restrict__ W_fc,
    const float* __restrict__ b_fc, float* __restrict__ out)
{
    __shared__ _Float16 hbuf[2][32];
    __shared__ _Float16 xbuf[2][2][32];

    const int lane = threadIdx.x & 63;
    const int li   = lane & 31;
    const int half = lane >> 5;
    const int b    = blockIdx.x * 2 + half;
    const bool unit = (li < HH);

    const float* ph0 = unit ? W_hh + (size_t)li * HH            : W_fc;
    const float* ph1 = unit ? W_hh + (size_t)(HH + li) * HH     : W_fc + HH;
    const float* ph2 = unit ? W_hh + (size_t)(2 * HH + li) * HH : nullptr;
    const float* px0 = unit ? W_ih + (size_t)li * HH            : nullptr;
    const float* px1 = unit ? W_ih + (size_t)(HH + li) * HH     : nullptr;
    const float* px2 = unit ? W_ih + (size_t)(2 * HH + li) * HH : nullptr;

    hf2 wh0[16], wh1[16], wh2[16], wx0[16], wx1[16], wx2[16];
#pragma unroll
    for (int m = 0; m < 16; ++m) {
        auto pk = [&](const float* p) -> hf2 {
            hf2 r;
            r.x = p ? (_Float16)p[2 * m] : (_Float16)0.f;
            r.y = (p && (2 * m + 1) < HH) ? (_Float16)p[2 * m + 1] : (_Float16)0.f;
            return r;
        };
        wh0[m] = pk(ph0); wh1[m] = pk(ph1); wh2[m] = pk(ph2);
        wx0[m] = pk(px0); wx1[m] = pk(px1); wx2[m] = pk(px2);
    }

    float arH0, azH0, anH0, anX0;
    if (unit) {
        arH0 = b_ih[li] + b_hh[li];
        azH0 = b_ih[HH + li] + b_hh[HH + li];
        anH0 = b_hh[2 * HH + li];
        anX0 = b_ih[2 * HH + li];
    } else {
        arH0 = b_fc[0]; azH0 = b_fc[1]; anH0 = 0.f; anX0 = 0.f;
    }

    const float* xb   = x + (size_t)b * TT * HH;
    float*       outb = out + (size_t)b * TT * 2;

    hbuf[half][li]    = (_Float16)0.f;
    xbuf[0][half][li] = unit ? (_Float16)xb[li]      : (_Float16)0.f;
    xbuf[1][half][li] = unit ? (_Float16)xb[HH + li] : (_Float16)0.f;
    MEMFENCE;
    float xpre = unit ? xb[(size_t)2 * HH + li] : 0.f;
    float hval = 0.f;

    const int4* HP  = (const int4*)(&hbuf[half][0]);
    const int4* XB0 = (const int4*)(&xbuf[0][half][0]);
    const int4* XB1 = (const int4*)(&xbuf[1][half][0]);

    int4 xq0 = XB0[0], xq1 = XB0[1], xq2 = XB0[2], xq3 = XB0[3];

#pragma unroll 2
    for (int t = 0; t < TT; ++t) {
        int4 hq0 = HP[0], hq1 = HP[1], hq2 = HP[2], hq3 = HP[3];

        float arH = arH0, azH = azH0, anH = anH0;
        float arX = 0.f, azX = 0.f, anX = anX0;
#define STEPM(m, hp, xp) \
        arH = dot2(hp, wh0[m], arH); azH = dot2(hp, wh1[m], azH); \
        anH = dot2(hp, wh2[m], anH); arX = dot2(xp, wx0[m], arX); \
        azX = dot2(xp, wx1[m], azX); anX = dot2(xp, wx2[m], anX);
        STEPM(0,  hq0.x, xq0.x) STEPM(1,  hq0.y, xq0.y)
        STEPM(2,  hq0.z, xq0.z) STEPM(3,  hq0.w, xq0.w)
        STEPM(4,  hq1.x, xq1.x) STEPM(5,  hq1.y, xq1.y)
        STEPM(6,  hq1.z, xq1.z) STEPM(7,  hq1.w, xq1.w)
        STEPM(8,  hq2.x, xq2.x) STEPM(9,  hq2.y, xq2.y)
        STEPM(10, hq2.z, xq2.z) STEPM(11, hq2.w, xq2.w)
        STEPM(12, hq3.x, xq3.x) STEPM(13, hq3.y, xq3.y)
        STEPM(14, hq3.z, xq3.z) STEPM(15, hq3.w, xq3.w)
#undef STEPM

        const float sumr = arH + arX;
        const float sumz = azH + azX;
        if (lane == 31 && t > 0)
            *(float2*)(outb + (size_t)(t - 1) * 2) = make_float2(sumr, sumz);

        const float r    = __fdividef(1.f, 1.f + __expf(-sumr));
        const float z    = __fdividef(1.f, 1.f + __expf(-sumz));
        const float npre = fmaf(r, anH, anX);
        const float nn   = __fdividef(2.f, 1.f + __expf(-2.f * npre)) - 1.f;
        const float hnew = nn + z * (hval - nn);
        hval = unit ? hnew : 0.f;
        hbuf[half][li] = (_Float16)hval;

        xbuf[t & 1][half][li] = unit ? (_Float16)xpre : (_Float16)0.f;
        MEMFENCE;
        int tn = t + 3; if (tn > TT - 1) tn = TT - 1;
        xpre = unit ? xb[(size_t)tn * HH + li] : 0.f;

        const int4* XN = (t & 1) ? XB0 : XB1;
        xq0 = XN[0]; xq1 = XN[1]; xq2 = XN[2]; xq3 = XN[3];
    }

    {
        int4 hq0 = HP[0], hq1 = HP[1], hq2 = HP[2], hq3 = HP[3];
        float f0 = arH0, f1 = azH0;
#define FST(m, hp) f0 = dot2(hp, wh0[m], f0); f1 = dot2(hp, wh1[m], f1);
        FST(0,  hq0.x) FST(1,  hq0.y) FST(2,  hq0.z) FST(3,  hq0.w)
        FST(4,  hq1.x) FST(5,  hq1.y) FST(6,  hq1.z) FST(7,  hq1.w)
        FST(8,  hq2.x) FST(9,  hq2.y) FST(10, hq2.z) FST(11, hq2.w)
        FST(12, hq3.x) FST(13, hq3.y) FST(14, hq3.z) FST(15, hq3.w)
#undef FST
        if (lane == 31)
            *(float2*)(outb + (size_t)(TT - 1) * 2) = make_float2(f0, f1);
    }
}

extern "C" void kernel_launch(void* const* d_in, const int* in_sizes, int n_in,
                              void* d_out, int out_size, void* d_ws, size_t ws_size,
                              hipStream_t stream) {
    const float* x    = (const float*)d_in[0];
    const float* W_ih = (const float*)d_in[1];
    const float* W_hh = (const float*)d_in[2];
    const float* b_ih = (const float*)d_in[3];
    const float* b_hh = (const float*)d_in[4];
    const float* W_fc = (const float*)d_in[5];
    const float* b_fc = (const float*)d_in[6];
    float* out = (float*)d_out;

    if (ws_size >= WS_NEEDED) {
        _Float16* xg = (_Float16*)d_ws;
        int* wpk = (int*)((char*)d_ws + XG_BYTES);
        pack_wih_kernel<<<(WPAIRS + 255) / 256, 256, 0, stream>>>(W_ih, wpk);
        xg_gemm_kernel<<<BB, 128, 0, stream>>>(x, wpk, b_ih, xg);
        gru_rec2_kernel<<<BB, 128, 0, stream>>>(xg, W_hh, b_hh, W_fc, b_fc, out);
    } else {
        gru_pair_kernel<<<BB / 2, 64, 0, stream>>>(x, W_ih, W_hh, b_ih, b_hh,
                                                   W_fc, b_fc, out);
    }
}